// Round 3
// baseline (1759.091 us; speedup 1.0000x reference)
//
#include <hip/hip_runtime.h>
#include <hip/hip_fp16.h>
#include <hip/hip_cooperative_groups.h>

namespace cg = cooperative_groups;

#define N_ENTITY 64368
#define N_REL 40
#define DIM 128
#define N_BASES 8
#define N_EDGES 500000
#define BATCH 64
#define SEED_LEN 32
#define NROWS (BATCH * SEED_LEN)            // 2048
#define SCAN_NB ((N_ENTITY + 255) / 256)    // 252
#define NPAD (SCAN_NB * 256)                // 64512 (block-aligned entity count)
#define G_COOP 1024                         // 4 blocks/CU x 256 CU, co-resident

struct alignas(8) half4 { __half2 lo, hi; };

// ===========================================================================
// MAIN PATH: ONE cooperative kernel for the whole RGCN.
// Phases (grid.sync between):
//   P0 zero hist        P1 histogram        P2 per-chunk scan
//   P3 apply prefix     P4 scatter          P5 phaseA (src-major msg write)
//   P6 phaseB (dst gather + mean + root + bias)
// ===========================================================================
__global__ __launch_bounds__(256, 4) void k_rgcn_all(
    const int* __restrict__ esrc, const int* __restrict__ edst,
    const int* __restrict__ etype, const float* __restrict__ basis,
    const float* __restrict__ att, const float* __restrict__ root,
    const float* __restrict__ bias,
    int* __restrict__ hist2, int* __restrict__ ptr2, int* __restrict__ work2,
    int* __restrict__ part2, int* __restrict__ ptype, int* __restrict__ idx,
    __half* __restrict__ msg, float* __restrict__ agg)
{
    cg::grid_group grid = cg::this_grid();
    __shared__ int s[256];
    __shared__ float att_s[N_REL * N_BASES];

    const int tid = threadIdx.x;
    const int bid = blockIdx.x;
    const int G   = gridDim.x;
    const int gsz = G * 256;
    const int gid = bid * 256 + tid;

    // ---- P0: zero histograms; stage att into LDS ----
    for (int i = gid; i < 2 * NPAD; i += gsz) hist2[i] = 0;
    for (int i = tid; i < N_REL * N_BASES; i += 256) att_s[i] = att[i];
    __threadfence();
    grid.sync();

    // ---- P1: histogram (dst at 0, src at NPAD) ----
    for (int e = gid; e < N_EDGES; e += gsz) {
        atomicAdd(&hist2[edst[e]], 1);
        atomicAdd(&hist2[NPAD + esrc[e]], 1);
    }
    __threadfence();
    grid.sync();

    // ---- P2: per-chunk exclusive scan (2*SCAN_NB chunks of 256) ----
    for (int c = bid; c < 2 * SCAN_NB; c += G) {
        int v = hist2[c * 256 + tid];
        s[tid] = v;
        __syncthreads();
        for (int off = 1; off < 256; off <<= 1) {
            int t = (tid >= off) ? s[tid - off] : 0;
            __syncthreads();
            s[tid] += t;
            __syncthreads();
        }
        ptr2[c * 256 + tid] = s[tid] - v;          // chunk-exclusive
        if (tid == 255) part2[c] = s[255];
        __syncthreads();
    }
    __threadfence();
    grid.sync();

    // ---- P3: add per-half chunk prefix; finalize ptr2/work2 ----
    for (int c = bid; c < 2 * SCAN_NB; c += G) {
        int cstart = (c < SCAN_NB) ? 0 : SCAN_NB;  // halves scanned independently
        int sum = 0;
        for (int k = cstart + tid; k < c; k += 256) sum += part2[k];
        s[tid] = sum;
        __syncthreads();
        for (int off = 128; off > 0; off >>= 1) {
            if (tid < off) s[tid] += s[tid + off];
            __syncthreads();
        }
        int p = ptr2[c * 256 + tid] + s[0];
        ptr2[c * 256 + tid]  = p;
        work2[c * 256 + tid] = p;
        __syncthreads();
    }
    __threadfence();
    grid.sync();

    // ---- P4: scatter (ptype src-order, idx dst->src permutation) ----
    for (int e = gid; e < N_EDGES; e += gsz) {
        int spos = atomicAdd(&work2[NPAD + esrc[e]], 1);
        int dpos = atomicAdd(&work2[edst[e]], 1);
        ptype[spos] = etype[e];
        idx[dpos]   = spos;
    }
    __threadfence();
    grid.sync();

    // ---- P5: phase A — half-wave per src; streaming basis read + msg write ----
    {
        const int l32 = tid & 31;
        const int* sptr  = ptr2 + NPAD;
        const int* shist = hist2 + NPAD;
        const size_t bstride = (size_t)N_ENTITY * DIM;

        for (int sid = (bid << 3) + (tid >> 5); sid < N_ENTITY; sid += (G << 3)) {
            int cnt = shist[sid];
            if (cnt == 0) continue;
            int p = sptr[sid];

            const float* bp = basis + (size_t)sid * DIM + l32 * 4;
            float4 r0 = *(const float4*)(bp + 0 * bstride);
            float4 r1 = *(const float4*)(bp + 1 * bstride);
            float4 r2 = *(const float4*)(bp + 2 * bstride);
            float4 r3 = *(const float4*)(bp + 3 * bstride);
            float4 r4 = *(const float4*)(bp + 4 * bstride);
            float4 r5 = *(const float4*)(bp + 5 * bstride);
            float4 r6 = *(const float4*)(bp + 6 * bstride);
            float4 r7 = *(const float4*)(bp + 7 * bstride);

            int j = 0;
            for (; j + 1 < cnt; j += 2) {
                int tA = ptype[p + j];
                int tB = ptype[p + j + 1];
                const float* cA = att_s + tA * N_BASES;
                const float* cB = att_s + tB * N_BASES;
                float4 cA0 = *(const float4*)(cA);
                float4 cA1 = *(const float4*)(cA + 4);
                float4 cB0 = *(const float4*)(cB);
                float4 cB1 = *(const float4*)(cB + 4);

                float4 mA, mB;
                mA.x = cA0.x*r0.x + cA0.y*r1.x + cA0.z*r2.x + cA0.w*r3.x
                     + cA1.x*r4.x + cA1.y*r5.x + cA1.z*r6.x + cA1.w*r7.x;
                mA.y = cA0.x*r0.y + cA0.y*r1.y + cA0.z*r2.y + cA0.w*r3.y
                     + cA1.x*r4.y + cA1.y*r5.y + cA1.z*r6.y + cA1.w*r7.y;
                mA.z = cA0.x*r0.z + cA0.y*r1.z + cA0.z*r2.z + cA0.w*r3.z
                     + cA1.x*r4.z + cA1.y*r5.z + cA1.z*r6.z + cA1.w*r7.z;
                mA.w = cA0.x*r0.w + cA0.y*r1.w + cA0.z*r2.w + cA0.w*r3.w
                     + cA1.x*r4.w + cA1.y*r5.w + cA1.z*r6.w + cA1.w*r7.w;
                mB.x = cB0.x*r0.x + cB0.y*r1.x + cB0.z*r2.x + cB0.w*r3.x
                     + cB1.x*r4.x + cB1.y*r5.x + cB1.z*r6.x + cB1.w*r7.x;
                mB.y = cB0.x*r0.y + cB0.y*r1.y + cB0.z*r2.y + cB0.w*r3.y
                     + cB1.x*r4.y + cB1.y*r5.y + cB1.z*r6.y + cB1.w*r7.y;
                mB.z = cB0.x*r0.z + cB0.y*r1.z + cB0.z*r2.z + cB0.w*r3.z
                     + cB1.x*r4.z + cB1.y*r5.z + cB1.z*r6.z + cB1.w*r7.z;
                mB.w = cB0.x*r0.w + cB0.y*r1.w + cB0.z*r2.w + cB0.w*r3.w
                     + cB1.x*r4.w + cB1.y*r5.w + cB1.z*r6.w + cB1.w*r7.w;

                half4 hA, hB;
                hA.lo = __floats2half2_rn(mA.x, mA.y);
                hA.hi = __floats2half2_rn(mA.z, mA.w);
                hB.lo = __floats2half2_rn(mB.x, mB.y);
                hB.hi = __floats2half2_rn(mB.z, mB.w);
                *(half4*)(msg + ((size_t)(p + j)     << 7) + (l32 << 2)) = hA;
                *(half4*)(msg + ((size_t)(p + j + 1) << 7) + (l32 << 2)) = hB;
            }
            if (j < cnt) {
                int tA = ptype[p + j];
                const float* cA = att_s + tA * N_BASES;
                float4 cA0 = *(const float4*)(cA);
                float4 cA1 = *(const float4*)(cA + 4);
                float4 mA;
                mA.x = cA0.x*r0.x + cA0.y*r1.x + cA0.z*r2.x + cA0.w*r3.x
                     + cA1.x*r4.x + cA1.y*r5.x + cA1.z*r6.x + cA1.w*r7.x;
                mA.y = cA0.x*r0.y + cA0.y*r1.y + cA0.z*r2.y + cA0.w*r3.y
                     + cA1.x*r4.y + cA1.y*r5.y + cA1.z*r6.y + cA1.w*r7.y;
                mA.z = cA0.x*r0.z + cA0.y*r1.z + cA0.z*r2.z + cA0.w*r3.z
                     + cA1.x*r4.z + cA1.y*r5.z + cA1.z*r6.z + cA1.w*r7.z;
                mA.w = cA0.x*r0.w + cA0.y*r1.w + cA0.z*r2.w + cA0.w*r3.w
                     + cA1.x*r4.w + cA1.y*r5.w + cA1.z*r6.w + cA1.w*r7.w;
                half4 hA;
                hA.lo = __floats2half2_rn(mA.x, mA.y);
                hA.hi = __floats2half2_rn(mA.z, mA.w);
                *(half4*)(msg + ((size_t)(p + j) << 7) + (l32 << 2)) = hA;
            }
        }
    }
    __threadfence();
    grid.sync();

    // ---- P6: phase B — wave per dst; gather via idx; mean + root + bias ----
    {
        const int lane = tid & 63;
        const __half2* mp = (const __half2*)msg;   // row r at r*64 + lane

        for (int wid = (bid << 2) + (tid >> 6); wid < N_ENTITY; wid += (G << 2)) {
            int cnt = hist2[wid];
            int p   = ptr2[wid];

            float ax = 0.f, ay = 0.f;
            int j = 0;
            for (; j + 3 < cnt; j += 4) {
                int i0 = idx[p + j + 0];
                int i1 = idx[p + j + 1];
                int i2 = idx[p + j + 2];
                int i3 = idx[p + j + 3];
                float2 f0 = __half22float2(mp[((size_t)i0 << 6) + lane]);
                float2 f1 = __half22float2(mp[((size_t)i1 << 6) + lane]);
                float2 f2 = __half22float2(mp[((size_t)i2 << 6) + lane]);
                float2 f3 = __half22float2(mp[((size_t)i3 << 6) + lane]);
                ax += (f0.x + f1.x) + (f2.x + f3.x);
                ay += (f0.y + f1.y) + (f2.y + f3.y);
            }
            for (; j < cnt; ++j) {
                int i0 = idx[p + j];
                float2 f = __half22float2(mp[((size_t)i0 << 6) + lane]);
                ax += f.x; ay += f.y;
            }

            float inv = 1.0f / fmaxf((float)cnt, 1.0f);
            int o = wid * DIM + lane * 2;
            float2 r  = *(const float2*)(root + o);
            float2 bb = *(const float2*)(bias + lane * 2);
            float2 outv;
            outv.x = ax * inv + r.x + bb.x;
            outv.y = ay * inv + r.y + bb.y;
            *(float2*)(agg + o) = outv;
        }
    }
}

// ===========================================================================
// Fused attention: T = tanh(H@A) kept in registers, e = T@b, softmax, u.
// One block per batch. A read from global (L2-hot: 64 blocks share 64 KB).
// ===========================================================================
__global__ __launch_bounds__(256) void k_attn(
    const int* __restrict__ seed_ids, const float* __restrict__ nodes,
    const float* __restrict__ A, const float* __restrict__ Bv,
    float* __restrict__ u, float* __restrict__ uT)
{
    __shared__ float Hs[SEED_LEN * DIM];   // 16 KB
    __shared__ float ew[SEED_LEN];
    __shared__ float attw[SEED_LEN];

    int b = blockIdx.x, tid = threadIdx.x;

    for (int i = tid; i < SEED_LEN * DIM; i += 256) {
        int ss = i >> 7, d = i & 127;
        Hs[i] = nodes[(size_t)seed_ids[b * SEED_LEN + ss] * DIM + d];
    }
    __syncthreads();

    int jx = tid & 31;          // col group: cols jx*4..+3
    int iy = tid >> 5;          // row group: rows iy*4..+3
    float acc[4][4] = {{0,0,0,0},{0,0,0,0},{0,0,0,0},{0,0,0,0}};

    for (int d = 0; d < DIM; ++d) {
        const float4 a4 = *(const float4*)(A + d * DIM + jx * 4);
        float h0 = Hs[(iy * 4 + 0) * DIM + d];
        float h1 = Hs[(iy * 4 + 1) * DIM + d];
        float h2 = Hs[(iy * 4 + 2) * DIM + d];
        float h3 = Hs[(iy * 4 + 3) * DIM + d];
        acc[0][0] += h0 * a4.x; acc[0][1] += h0 * a4.y;
        acc[0][2] += h0 * a4.z; acc[0][3] += h0 * a4.w;
        acc[1][0] += h1 * a4.x; acc[1][1] += h1 * a4.y;
        acc[1][2] += h1 * a4.z; acc[1][3] += h1 * a4.w;
        acc[2][0] += h2 * a4.x; acc[2][1] += h2 * a4.y;
        acc[2][2] += h2 * a4.z; acc[2][3] += h2 * a4.w;
        acc[3][0] += h3 * a4.x; acc[3][1] += h3 * a4.y;
        acc[3][2] += h3 * a4.z; acc[3][3] += h3 * a4.w;
    }

    const float4 bv = *(const float4*)(Bv + jx * 4);
    #pragma unroll
    for (int i = 0; i < 4; ++i) {
        float pe = tanhf(acc[i][0]) * bv.x + tanhf(acc[i][1]) * bv.y
                 + tanhf(acc[i][2]) * bv.z + tanhf(acc[i][3]) * bv.w;
        pe += __shfl_xor(pe, 1, 64);
        pe += __shfl_xor(pe, 2, 64);
        pe += __shfl_xor(pe, 4, 64);
        pe += __shfl_xor(pe, 8, 64);
        pe += __shfl_xor(pe, 16, 64);
        if (jx == 0) ew[iy * 4 + i] = pe;
    }
    __syncthreads();

    if (tid == 0) {
        float mx = -1e30f;
        for (int k = 0; k < SEED_LEN; ++k) mx = fmaxf(mx, ew[k]);
        float ssum = 0.0f;
        for (int k = 0; k < SEED_LEN; ++k) {
            float v = expf(ew[k] - mx);
            attw[k] = v; ssum += v;
        }
        float inv = 1.0f / ssum;
        for (int k = 0; k < SEED_LEN; ++k) attw[k] *= inv;
    }
    __syncthreads();

    if (tid < DIM) {
        float a = 0.0f;
        for (int k = 0; k < SEED_LEN; ++k) a += attw[k] * Hs[k * DIM + tid];
        u[b * DIM + tid]  = a;
        uT[tid * BATCH + b] = a;
    }
}

// ===========================================================================
// Scores: out[b][n] = u[b]·nodes[n] + out_bias[n]
// ===========================================================================
__global__ __launch_bounds__(256) void k_scores(
    const float* __restrict__ nodes, const float* __restrict__ uT,
    const float* __restrict__ out_bias, float* __restrict__ out)
{
    __shared__ float Nl[DIM * 65];

    int tid = threadIdx.x;
    int n0  = blockIdx.x * 64;

    for (int i = tid; i < 64 * DIM; i += 256) {
        int n = i >> 7, d = i & 127;
        int gn = n0 + n;
        Nl[d * 65 + n] = (gn < N_ENTITY) ? nodes[(size_t)gn * DIM + d] : 0.0f;
    }
    __syncthreads();

    int w    = __builtin_amdgcn_readfirstlane(tid >> 6);
    int lane = tid & 63;
    int b0   = w * 16;

    float acc[16];
    #pragma unroll
    for (int k = 0; k < 16; ++k) acc[k] = 0.0f;

    #pragma unroll 4
    for (int d = 0; d < DIM; ++d) {
        float nv = Nl[d * 65 + lane];
        const float* up = uT + d * BATCH + b0;
        #pragma unroll
        for (int k = 0; k < 16; ++k) acc[k] += up[k] * nv;
    }

    int gn = n0 + lane;
    if (gn < N_ENTITY) {
        float ob = out_bias[gn];
        #pragma unroll
        for (int k = 0; k < 16; ++k)
            out[(size_t)(b0 + k) * N_ENTITY + gn] = acc[k] + ob;
    }
}

// ===========================================================================
// FALLBACK PATH (only if ws can't hold msg): R2's multi-kernel dst gather.
// ===========================================================================
__global__ __launch_bounds__(256) void k_hist2F(
    const int* __restrict__ edst, const int* __restrict__ esrc,
    int* __restrict__ hist2)
{
    int e = blockIdx.x * 256 + threadIdx.x;
    if (e < N_EDGES) {
        atomicAdd(&hist2[edst[e]], 1);
        atomicAdd(&hist2[NPAD + esrc[e]], 1);
    }
}

__global__ __launch_bounds__(256) void k_scan1F(
    const int* __restrict__ hist2, int* __restrict__ ptr2,
    int* __restrict__ partial)
{
    __shared__ int s[256];
    int tid = threadIdx.x;
    int gid = blockIdx.x * 256 + tid;
    int v = hist2[gid];
    s[tid] = v;
    __syncthreads();
    for (int off = 1; off < 256; off <<= 1) {
        int t = (tid >= off) ? s[tid - off] : 0;
        __syncthreads();
        s[tid] += t;
        __syncthreads();
    }
    ptr2[gid] = s[tid] - v;
    if (tid == 255) partial[blockIdx.x] = s[255];
}

__global__ __launch_bounds__(256) void k_scan2F(
    const int* __restrict__ partial, int* __restrict__ poff)
{
    __shared__ int s[256];
    int tid = threadIdx.x;
    int base = blockIdx.x * SCAN_NB;
    int v = (tid < SCAN_NB) ? partial[base + tid] : 0;
    s[tid] = v;
    __syncthreads();
    for (int off = 1; off < 256; off <<= 1) {
        int t = (tid >= off) ? s[tid - off] : 0;
        __syncthreads();
        s[tid] += t;
        __syncthreads();
    }
    if (tid < SCAN_NB) poff[base + tid] = s[tid] - v;
}

__global__ __launch_bounds__(256) void k_scan3F(
    int* __restrict__ ptr2, const int* __restrict__ poff,
    int* __restrict__ work2)
{
    int gid = blockIdx.x * 256 + threadIdx.x;
    int p = ptr2[gid] + poff[blockIdx.x];
    ptr2[gid] = p;
    work2[gid] = p;
}

__global__ __launch_bounds__(256) void k_scatterD(
    const int* __restrict__ esrc, const int* __restrict__ edst,
    const int* __restrict__ etype, int* __restrict__ work2,
    int* __restrict__ meta)
{
    int e = blockIdx.x * 256 + threadIdx.x;
    if (e < N_EDGES) {
        int pos = atomicAdd(&work2[edst[e]], 1);
        meta[pos] = esrc[e] * 64 + etype[e];
    }
}

#define ACC8(C0, C1, V0, V1, V2, V3, V4, V5, V6, V7)                         \
    acc.x += C0.x*V0.x + C0.y*V1.x + C0.z*V2.x + C0.w*V3.x                   \
           + C1.x*V4.x + C1.y*V5.x + C1.z*V6.x + C1.w*V7.x;                  \
    acc.y += C0.x*V0.y + C0.y*V1.y + C0.z*V2.y + C0.w*V3.y                   \
           + C1.x*V4.y + C1.y*V5.y + C1.z*V6.y + C1.w*V7.y;                  \
    acc.z += C0.x*V0.z + C0.y*V1.z + C0.z*V2.z + C0.w*V3.z                   \
           + C1.x*V4.z + C1.y*V5.z + C1.z*V6.z + C1.w*V7.z;                  \
    acc.w += C0.x*V0.w + C0.y*V1.w + C0.z*V2.w + C0.w*V3.w                   \
           + C1.x*V4.w + C1.y*V5.w + C1.z*V6.w + C1.w*V7.w;

__global__ __launch_bounds__(256) void k_gather(
    const int* __restrict__ ptr, const int* __restrict__ hist,
    const int* __restrict__ meta, const float* __restrict__ basis,
    const float* __restrict__ att, const float* __restrict__ root,
    const float* __restrict__ bias, float* __restrict__ agg)
{
    __shared__ float att_s[N_REL * N_BASES];
    int tid = threadIdx.x;
    for (int i = tid; i < N_REL * N_BASES; i += 256) att_s[i] = att[i];
    __syncthreads();

    int wid  = (int)((blockIdx.x * 256 + tid) >> 6);
    int lane = tid & 63;
    if (wid >= N_ENTITY) return;

    int half = lane >> 5;
    int l32  = lane & 31;
    int p   = ptr[wid];
    int cnt = hist[wid];
    const size_t bstride = (size_t)N_ENTITY * DIM;

    float4 acc = {0.f, 0.f, 0.f, 0.f};
    int j = 0;
    for (; j + 3 < cnt; j += 4) {
        int mA0 = meta[p + j + 0];
        int mA1 = meta[p + j + 1];
        int mB0 = meta[p + j + 2];
        int mB1 = meta[p + j + 3];
        int mA = half ? mA1 : mA0;
        int mB = half ? mB1 : mB0;
        const float* bA = basis + (size_t)(mA >> 6) * DIM + l32 * 4;
        const float* bB = basis + (size_t)(mB >> 6) * DIM + l32 * 4;
        float4 a0 = *(const float4*)(bA + 0 * bstride);
        float4 a1 = *(const float4*)(bA + 1 * bstride);
        float4 a2 = *(const float4*)(bA + 2 * bstride);
        float4 a3 = *(const float4*)(bA + 3 * bstride);
        float4 a4 = *(const float4*)(bA + 4 * bstride);
        float4 a5 = *(const float4*)(bA + 5 * bstride);
        float4 a6 = *(const float4*)(bA + 6 * bstride);
        float4 a7 = *(const float4*)(bA + 7 * bstride);
        float4 b0 = *(const float4*)(bB + 0 * bstride);
        float4 b1 = *(const float4*)(bB + 1 * bstride);
        float4 b2 = *(const float4*)(bB + 2 * bstride);
        float4 b3 = *(const float4*)(bB + 3 * bstride);
        float4 b4 = *(const float4*)(bB + 4 * bstride);
        float4 b5 = *(const float4*)(bB + 5 * bstride);
        float4 b6 = *(const float4*)(bB + 6 * bstride);
        float4 b7 = *(const float4*)(bB + 7 * bstride);
        float4 cA0 = *(const float4*)(att_s + (mA & 63) * N_BASES);
        float4 cA1 = *(const float4*)(att_s + (mA & 63) * N_BASES + 4);
        float4 cB0 = *(const float4*)(att_s + (mB & 63) * N_BASES);
        float4 cB1 = *(const float4*)(att_s + (mB & 63) * N_BASES + 4);
        ACC8(cA0, cA1, a0, a1, a2, a3, a4, a5, a6, a7)
        ACC8(cB0, cB1, b0, b1, b2, b3, b4, b5, b6, b7)
    }
    for (; j < cnt; j += 2) {
        int m0 = meta[p + j];
        bool has1 = (j + 1 < cnt);
        int m1 = has1 ? meta[p + j + 1] : m0;
        int m = half ? m1 : m0;
        float sc = (half && !has1) ? 0.0f : 1.0f;
        const float* bA = basis + (size_t)(m >> 6) * DIM + l32 * 4;
        float4 a0 = *(const float4*)(bA + 0 * bstride);
        float4 a1 = *(const float4*)(bA + 1 * bstride);
        float4 a2 = *(const float4*)(bA + 2 * bstride);
        float4 a3 = *(const float4*)(bA + 3 * bstride);
        float4 a4 = *(const float4*)(bA + 4 * bstride);
        float4 a5 = *(const float4*)(bA + 5 * bstride);
        float4 a6 = *(const float4*)(bA + 6 * bstride);
        float4 a7 = *(const float4*)(bA + 7 * bstride);
        float4 c0 = *(const float4*)(att_s + (m & 63) * N_BASES);
        float4 c1 = *(const float4*)(att_s + (m & 63) * N_BASES + 4);
        c0.x *= sc; c0.y *= sc; c0.z *= sc; c0.w *= sc;
        c1.x *= sc; c1.y *= sc; c1.z *= sc; c1.w *= sc;
        ACC8(c0, c1, a0, a1, a2, a3, a4, a5, a6, a7)
    }

    acc.x += __shfl_xor(acc.x, 32, 64);
    acc.y += __shfl_xor(acc.y, 32, 64);
    acc.z += __shfl_xor(acc.z, 32, 64);
    acc.w += __shfl_xor(acc.w, 32, 64);

    if (half == 0) {
        float inv = 1.0f / fmaxf((float)cnt, 1.0f);
        int o = wid * DIM + l32 * 4;
        float4 r  = *(const float4*)(root + o);
        float4 bb = *(const float4*)(bias + l32 * 4);
        float4 outv;
        outv.x = acc.x * inv + r.x + bb.x;
        outv.y = acc.y * inv + r.y + bb.y;
        outv.z = acc.z * inv + r.z + bb.z;
        outv.w = acc.w * inv + r.w + bb.w;
        *(float4*)(agg + o) = outv;
    }
}

// ===========================================================================
extern "C" void kernel_launch(void* const* d_in, const int* in_sizes, int n_in,
                              void* d_out, int out_size, void* d_ws, size_t ws_size,
                              hipStream_t stream)
{
    const int*   seed_ids  = (const int*)d_in[0];
    const int*   esrc      = (const int*)d_in[1];
    const int*   edst      = (const int*)d_in[2];
    const int*   etype     = (const int*)d_in[3];
    const float* basis     = (const float*)d_in[4];
    const float* att       = (const float*)d_in[5];
    const float* root      = (const float*)d_in[6];
    const float* rgcn_bias = (const float*)d_in[7];
    const float* attn_a    = (const float*)d_in[8];
    const float* attn_b    = (const float*)d_in[9];
    const float* out_bias  = (const float*)d_in[10];
    float* out = (float*)d_out;

    const size_t AGG_F  = (size_t)N_ENTITY * DIM;        // 8,239,104 words
    const size_t MSG_W  = (size_t)N_EDGES * 64;          // fp16 msg in words
    const size_t H2_I   = (size_t)2 * NPAD;              // 129,024

    const size_t main_words = AGG_F + MSG_W + 3 * H2_I + 1024
                            + 2 * (size_t)N_EDGES + 2 * BATCH * DIM;
    bool big = ws_size >= main_words * 4;

    if (big) {
        float*  agg    = (float*)d_ws;
        __half* msg    = (__half*)(agg + AGG_F);
        int*    hist2  = (int*)(agg + AGG_F + MSG_W);
        int*    ptr2   = hist2 + H2_I;
        int*    work2  = ptr2 + H2_I;
        int*    part2  = work2 + H2_I;    // 512
        int*    ptype  = part2 + 1024;    // N_EDGES
        int*    idx    = ptype + N_EDGES; // N_EDGES
        float*  u      = (float*)(idx + N_EDGES);
        float*  uT     = u + BATCH * DIM;

        void* kargs[] = {
            (void*)&esrc, (void*)&edst, (void*)&etype, (void*)&basis,
            (void*)&att, (void*)&root, (void*)&rgcn_bias,
            (void*)&hist2, (void*)&ptr2, (void*)&work2, (void*)&part2,
            (void*)&ptype, (void*)&idx, (void*)&msg, (void*)&agg
        };
        hipLaunchCooperativeKernel((void*)k_rgcn_all, dim3(G_COOP), dim3(256),
                                   kargs, 0, stream);

        k_attn<<<BATCH, 256, 0, stream>>>(seed_ids, agg, attn_a, attn_b, u, uT);
        k_scores<<<(N_ENTITY + 63) / 64, 256, 0, stream>>>(agg, uT, out_bias, out);
    } else {
        // fallback: dst-major gather (no msg buffer), multi-kernel
        float* agg     = (float*)d_ws;
        int*   hist2   = (int*)(agg + AGG_F);
        int*   ptr2    = hist2 + H2_I;
        int*   work2   = ptr2 + H2_I;
        int*   part2   = work2 + H2_I;
        int*   poff2   = part2 + 512;
        int*   meta    = poff2 + 512;
        float* u       = (float*)(meta + N_EDGES);
        float* uT      = u + BATCH * DIM;

        hipMemsetAsync(hist2, 0, H2_I * sizeof(int), stream);
        k_hist2F<<<(N_EDGES + 255) / 256, 256, 0, stream>>>(edst, esrc, hist2);
        k_scan1F<<<2 * SCAN_NB, 256, 0, stream>>>(hist2, ptr2, part2);
        k_scan2F<<<2, 256, 0, stream>>>(part2, poff2);
        k_scan3F<<<2 * SCAN_NB, 256, 0, stream>>>(ptr2, poff2, work2);
        k_scatterD<<<(N_EDGES + 255) / 256, 256, 0, stream>>>(
            esrc, edst, etype, work2, meta);

        k_gather<<<(N_ENTITY * 64 + 255) / 256, 256, 0, stream>>>(
            ptr2, hist2, meta, basis, att, root, rgcn_bias, agg);

        k_attn<<<BATCH, 256, 0, stream>>>(seed_ids, agg, attn_a, attn_b, u, uT);
        k_scores<<<(N_ENTITY + 63) / 64, 256, 0, stream>>>(agg, uT, out_bias, out);
    }
}

// Round 4
// 637.958 us; speedup vs baseline: 2.7574x; 2.7574x over previous
//
#include <hip/hip_runtime.h>
#include <hip/hip_fp16.h>

#define N_ENTITY 64368
#define N_REL 40
#define DIM 128
#define N_BASES 8
#define N_EDGES 500000
#define BATCH 64
#define SEED_LEN 32
#define NROWS (BATCH * SEED_LEN)            // 2048
#define SCAN_NB ((N_ENTITY + 255) / 256)    // 252
#define NPAD (SCAN_NB * 256)                // 64512 (block-aligned entity count)

#define CAP 64                               // slot capacity per dst (Poisson(7.8), max~28)
#define OVF_CAP 4096                         // overflow list capacity (never hit in practice)
#define SCAT_BLOCKS ((N_EDGES + 255) / 256)  // 1954
#define CVT_BLOCKS 2048

struct alignas(8) h4 { __half2 lo, hi; };

// ===========================================================================
// K1: fused {edge scatter into capacity-padded dst buckets} || {basis fp32 ->
// fp16 transpose-convert to [entity][base][dim]}. The two halves are
// independent; disjoint block ranges run them concurrently in ONE dispatch.
// ===========================================================================
__global__ __launch_bounds__(256) void k_prep(
    const int* __restrict__ esrc, const int* __restrict__ edst,
    const int* __restrict__ etype, const float* __restrict__ basis,
    __half* __restrict__ basis16, int* __restrict__ cnt,
    int* __restrict__ novf, int* __restrict__ ovf, int* __restrict__ slots)
{
    int bid = blockIdx.x, tid = threadIdx.x;
    if (bid < SCAT_BLOCKS) {
        // ---- edge scatter: k = atomicAdd(cnt[dst]); slots[dst*CAP+k]=meta ----
        int e = bid * 256 + tid;
        if (e < N_EDGES) {
            int d = edst[e];
            int meta = esrc[e] * 64 + etype[e];      // src<2^17 -> meta<2^23
            int k = atomicAdd(&cnt[d], 1);
            if (k < CAP) {
                slots[(size_t)d * CAP + k] = meta;
            } else {                                  // statistically impossible;
                int o = atomicAdd(novf, 1);           // kept for correctness
                if (o < OVF_CAP) { ovf[2 * o] = d; ovf[2 * o + 1] = meta; }
            }
        }
    } else {
        // ---- basis convert: wave per entity, 8 planes -> contiguous 2KB ----
        int wv   = ((bid - SCAT_BLOCKS) << 2) + (tid >> 6);
        int lane = tid & 63;
        const size_t bstride = (size_t)N_ENTITY * DIM;
        for (int e = wv; e < N_ENTITY; e += (CVT_BLOCKS << 2)) {
            const float* sp = basis + (size_t)e * DIM + lane * 2;
            __half* dp = basis16 + ((size_t)e << 10) + lane * 2;
            #pragma unroll
            for (int b = 0; b < 8; ++b) {
                float2 v = *(const float2*)(sp + b * bstride);
                *(__half2*)(dp + (b << 7)) = __floats2half2_rn(v.x, v.y);
            }
        }
    }
}

// ===========================================================================
// K2: dst-major gather. One wave per dst; half-wave per edge, 2 edges deep.
// Per edge: 8x8B contiguous-block loads from LLC-resident basis16[src],
// fp32 accumulate with att coefficients; fused mean + root + bias.
// ===========================================================================
__device__ __forceinline__ void acc_edge(
    const __half* __restrict__ p, float4 c0, float4 c1, float4& acc)
{
    h4 h0 = *(const h4*)(p + 0 * DIM);
    h4 h1 = *(const h4*)(p + 1 * DIM);
    h4 h2 = *(const h4*)(p + 2 * DIM);
    h4 h3 = *(const h4*)(p + 3 * DIM);
    h4 h4_ = *(const h4*)(p + 4 * DIM);
    h4 h5 = *(const h4*)(p + 5 * DIM);
    h4 h6 = *(const h4*)(p + 6 * DIM);
    h4 h7 = *(const h4*)(p + 7 * DIM);
    float2 f;
    f = __half22float2(h0.lo); acc.x += c0.x*f.x; acc.y += c0.x*f.y;
    f = __half22float2(h0.hi); acc.z += c0.x*f.x; acc.w += c0.x*f.y;
    f = __half22float2(h1.lo); acc.x += c0.y*f.x; acc.y += c0.y*f.y;
    f = __half22float2(h1.hi); acc.z += c0.y*f.x; acc.w += c0.y*f.y;
    f = __half22float2(h2.lo); acc.x += c0.z*f.x; acc.y += c0.z*f.y;
    f = __half22float2(h2.hi); acc.z += c0.z*f.x; acc.w += c0.z*f.y;
    f = __half22float2(h3.lo); acc.x += c0.w*f.x; acc.y += c0.w*f.y;
    f = __half22float2(h3.hi); acc.z += c0.w*f.x; acc.w += c0.w*f.y;
    f = __half22float2(h4_.lo); acc.x += c1.x*f.x; acc.y += c1.x*f.y;
    f = __half22float2(h4_.hi); acc.z += c1.x*f.x; acc.w += c1.x*f.y;
    f = __half22float2(h5.lo); acc.x += c1.y*f.x; acc.y += c1.y*f.y;
    f = __half22float2(h5.hi); acc.z += c1.y*f.x; acc.w += c1.y*f.y;
    f = __half22float2(h6.lo); acc.x += c1.z*f.x; acc.y += c1.z*f.y;
    f = __half22float2(h6.hi); acc.z += c1.z*f.x; acc.w += c1.z*f.y;
    f = __half22float2(h7.lo); acc.x += c1.w*f.x; acc.y += c1.w*f.y;
    f = __half22float2(h7.hi); acc.z += c1.w*f.x; acc.w += c1.w*f.y;
}

__global__ __launch_bounds__(256) void k_gather16(
    const int* __restrict__ cnt, const int* __restrict__ novf,
    const int* __restrict__ ovf, const int* __restrict__ slots,
    const __half* __restrict__ basis16, const float* __restrict__ att,
    const float* __restrict__ root, const float* __restrict__ bias,
    float* __restrict__ agg)
{
    __shared__ float att_s[N_REL * N_BASES];
    int tid = threadIdx.x;
    for (int i = tid; i < N_REL * N_BASES; i += 256) att_s[i] = att[i];
    __syncthreads();

    int wid  = (int)((blockIdx.x * 256 + tid) >> 6);
    int lane = tid & 63;
    if (wid >= N_ENTITY) return;
    int half = lane >> 5;
    int l32  = lane & 31;

    int c = cnt[wid];
    int n = (c < CAP) ? c : CAP;
    const int* sl = slots + (size_t)wid * CAP;

    float4 acc = {0.f, 0.f, 0.f, 0.f};
    int j = 0;
    for (; j + 3 < n; j += 4) {                    // 2 edges per half-wave
        int m0 = sl[j], m1 = sl[j + 1], m2 = sl[j + 2], m3 = sl[j + 3];
        int mA = half ? m1 : m0;
        int mB = half ? m3 : m2;
        const __half* pA = basis16 + ((size_t)(mA >> 6) << 10) + (l32 << 2);
        const __half* pB = basis16 + ((size_t)(mB >> 6) << 10) + (l32 << 2);
        float4 cA0 = *(const float4*)(att_s + (mA & 63) * N_BASES);
        float4 cA1 = *(const float4*)(att_s + (mA & 63) * N_BASES + 4);
        float4 cB0 = *(const float4*)(att_s + (mB & 63) * N_BASES);
        float4 cB1 = *(const float4*)(att_s + (mB & 63) * N_BASES + 4);
        acc_edge(pA, cA0, cA1, acc);
        acc_edge(pB, cB0, cB1, acc);
    }
    for (; j < n; j += 2) {                        // tail: 1-2 edges
        int m0 = sl[j];
        bool has1 = (j + 1 < n);
        int m = half ? (has1 ? sl[j + 1] : m0) : m0;
        float sc = (half && !has1) ? 0.0f : 1.0f;
        const __half* p = basis16 + ((size_t)(m >> 6) << 10) + (l32 << 2);
        float4 c0 = *(const float4*)(att_s + (m & 63) * N_BASES);
        float4 c1 = *(const float4*)(att_s + (m & 63) * N_BASES + 4);
        c0.x *= sc; c0.y *= sc; c0.z *= sc; c0.w *= sc;
        c1.x *= sc; c1.y *= sc; c1.z *= sc; c1.w *= sc;
        acc_edge(p, c0, c1, acc);
    }
    if (c > CAP) {                                 // correctness path (p~0)
        int nov = *novf; if (nov > OVF_CAP) nov = OVF_CAP;
        for (int k = 0; k < nov; ++k) {
            if (ovf[2 * k] == wid) {
                int m = ovf[2 * k + 1];
                const __half* p = basis16 + ((size_t)(m >> 6) << 10) + (l32 << 2);
                float sc = half ? 0.0f : 1.0f;
                float4 c0 = *(const float4*)(att_s + (m & 63) * N_BASES);
                float4 c1 = *(const float4*)(att_s + (m & 63) * N_BASES + 4);
                c0.x *= sc; c0.y *= sc; c0.z *= sc; c0.w *= sc;
                c1.x *= sc; c1.y *= sc; c1.z *= sc; c1.w *= sc;
                acc_edge(p, c0, c1, acc);
            }
        }
    }

    acc.x += __shfl_xor(acc.x, 32, 64);
    acc.y += __shfl_xor(acc.y, 32, 64);
    acc.z += __shfl_xor(acc.z, 32, 64);
    acc.w += __shfl_xor(acc.w, 32, 64);

    if (half == 0) {
        float inv = 1.0f / fmaxf((float)c, 1.0f);
        int o = wid * DIM + l32 * 4;
        float4 r  = *(const float4*)(root + o);
        float4 bb = *(const float4*)(bias + l32 * 4);
        float4 outv;
        outv.x = acc.x * inv + r.x + bb.x;
        outv.y = acc.y * inv + r.y + bb.y;
        outv.z = acc.z * inv + r.z + bb.z;
        outv.w = acc.w * inv + r.w + bb.w;
        *(float4*)(agg + o) = outv;
    }
}

// ===========================================================================
// Fused attention: T = tanh(H@A) in registers, e = T@b, softmax, u.
// One block per batch. (verified in round 3)
// ===========================================================================
__global__ __launch_bounds__(256) void k_attn(
    const int* __restrict__ seed_ids, const float* __restrict__ nodes,
    const float* __restrict__ A, const float* __restrict__ Bv,
    float* __restrict__ uT)
{
    __shared__ float Hs[SEED_LEN * DIM];   // 16 KB
    __shared__ float ew[SEED_LEN];
    __shared__ float attw[SEED_LEN];

    int b = blockIdx.x, tid = threadIdx.x;

    for (int i = tid; i < SEED_LEN * DIM; i += 256) {
        int ss = i >> 7, d = i & 127;
        Hs[i] = nodes[(size_t)seed_ids[b * SEED_LEN + ss] * DIM + d];
    }
    __syncthreads();

    int jx = tid & 31;          // cols jx*4..+3
    int iy = tid >> 5;          // rows iy*4..+3
    float acc[4][4] = {{0,0,0,0},{0,0,0,0},{0,0,0,0},{0,0,0,0}};

    for (int d = 0; d < DIM; ++d) {
        const float4 a4 = *(const float4*)(A + d * DIM + jx * 4);
        float h0 = Hs[(iy * 4 + 0) * DIM + d];
        float h1 = Hs[(iy * 4 + 1) * DIM + d];
        float h2 = Hs[(iy * 4 + 2) * DIM + d];
        float h3 = Hs[(iy * 4 + 3) * DIM + d];
        acc[0][0] += h0 * a4.x; acc[0][1] += h0 * a4.y;
        acc[0][2] += h0 * a4.z; acc[0][3] += h0 * a4.w;
        acc[1][0] += h1 * a4.x; acc[1][1] += h1 * a4.y;
        acc[1][2] += h1 * a4.z; acc[1][3] += h1 * a4.w;
        acc[2][0] += h2 * a4.x; acc[2][1] += h2 * a4.y;
        acc[2][2] += h2 * a4.z; acc[2][3] += h2 * a4.w;
        acc[3][0] += h3 * a4.x; acc[3][1] += h3 * a4.y;
        acc[3][2] += h3 * a4.z; acc[3][3] += h3 * a4.w;
    }

    const float4 bv = *(const float4*)(Bv + jx * 4);
    #pragma unroll
    for (int i = 0; i < 4; ++i) {
        float pe = tanhf(acc[i][0]) * bv.x + tanhf(acc[i][1]) * bv.y
                 + tanhf(acc[i][2]) * bv.z + tanhf(acc[i][3]) * bv.w;
        pe += __shfl_xor(pe, 1, 64);
        pe += __shfl_xor(pe, 2, 64);
        pe += __shfl_xor(pe, 4, 64);
        pe += __shfl_xor(pe, 8, 64);
        pe += __shfl_xor(pe, 16, 64);
        if (jx == 0) ew[iy * 4 + i] = pe;
    }
    __syncthreads();

    if (tid == 0) {
        float mx = -1e30f;
        for (int k = 0; k < SEED_LEN; ++k) mx = fmaxf(mx, ew[k]);
        float ssum = 0.0f;
        for (int k = 0; k < SEED_LEN; ++k) {
            float v = expf(ew[k] - mx);
            attw[k] = v; ssum += v;
        }
        float inv = 1.0f / ssum;
        for (int k = 0; k < SEED_LEN; ++k) attw[k] *= inv;
    }
    __syncthreads();

    if (tid < DIM) {
        float a = 0.0f;
        for (int k = 0; k < SEED_LEN; ++k) a += attw[k] * Hs[k * DIM + tid];
        uT[tid * BATCH + b] = a;
    }
}

// ===========================================================================
// Scores: out[b][n] = u[b]·nodes[n] + out_bias[n]
// ===========================================================================
__global__ __launch_bounds__(256) void k_scores(
    const float* __restrict__ nodes, const float* __restrict__ uT,
    const float* __restrict__ out_bias, float* __restrict__ out)
{
    __shared__ float Nl[DIM * 65];

    int tid = threadIdx.x;
    int n0  = blockIdx.x * 64;

    for (int i = tid; i < 64 * DIM; i += 256) {
        int n = i >> 7, d = i & 127;
        int gn = n0 + n;
        Nl[d * 65 + n] = (gn < N_ENTITY) ? nodes[(size_t)gn * DIM + d] : 0.0f;
    }
    __syncthreads();

    int w    = __builtin_amdgcn_readfirstlane(tid >> 6);
    int lane = tid & 63;
    int b0   = w * 16;

    float acc[16];
    #pragma unroll
    for (int k = 0; k < 16; ++k) acc[k] = 0.0f;

    #pragma unroll 4
    for (int d = 0; d < DIM; ++d) {
        float nv = Nl[d * 65 + lane];
        const float* up = uT + d * BATCH + b0;
        #pragma unroll
        for (int k = 0; k < 16; ++k) acc[k] += up[k] * nv;
    }

    int gn = n0 + lane;
    if (gn < N_ENTITY) {
        float ob = out_bias[gn];
        #pragma unroll
        for (int k = 0; k < 16; ++k)
            out[(size_t)(b0 + k) * N_ENTITY + gn] = acc[k] + ob;
    }
}

// ===========================================================================
// FALLBACK PATH (tiny ws): dst counting sort + fp32 gather (verified earlier).
// ===========================================================================
__global__ __launch_bounds__(256) void k_histF(
    const int* __restrict__ edst, int* __restrict__ hist)
{
    int e = blockIdx.x * 256 + threadIdx.x;
    if (e < N_EDGES) atomicAdd(&hist[edst[e]], 1);
}

__global__ __launch_bounds__(256) void k_scan1F(
    const int* __restrict__ hist, int* __restrict__ ptr,
    int* __restrict__ partial)
{
    __shared__ int s[256];
    int tid = threadIdx.x;
    int gid = blockIdx.x * 256 + tid;
    int v = hist[gid];
    s[tid] = v;
    __syncthreads();
    for (int off = 1; off < 256; off <<= 1) {
        int t = (tid >= off) ? s[tid - off] : 0;
        __syncthreads();
        s[tid] += t;
        __syncthreads();
    }
    ptr[gid] = s[tid] - v;
    if (tid == 255) partial[blockIdx.x] = s[255];
}

__global__ __launch_bounds__(256) void k_scan23F(
    int* __restrict__ ptr, const int* __restrict__ partial,
    int* __restrict__ work)
{
    __shared__ int s[256];
    int tid = threadIdx.x;
    int c   = blockIdx.x;
    int sum = 0;
    for (int k = tid; k < c; k += 256) sum += partial[k];
    s[tid] = sum;
    __syncthreads();
    for (int off = 128; off > 0; off >>= 1) {
        if (tid < off) s[tid] += s[tid + off];
        __syncthreads();
    }
    int p = ptr[c * 256 + tid] + s[0];
    ptr[c * 256 + tid]  = p;
    work[c * 256 + tid] = p;
}

__global__ __launch_bounds__(256) void k_scatterF(
    const int* __restrict__ esrc, const int* __restrict__ edst,
    const int* __restrict__ etype, int* __restrict__ work,
    int* __restrict__ meta)
{
    int e = blockIdx.x * 256 + threadIdx.x;
    if (e < N_EDGES) {
        int pos = atomicAdd(&work[edst[e]], 1);
        meta[pos] = esrc[e] * 64 + etype[e];
    }
}

#define ACC8(C0, C1, V0, V1, V2, V3, V4, V5, V6, V7)                         \
    acc.x += C0.x*V0.x + C0.y*V1.x + C0.z*V2.x + C0.w*V3.x                   \
           + C1.x*V4.x + C1.y*V5.x + C1.z*V6.x + C1.w*V7.x;                  \
    acc.y += C0.x*V0.y + C0.y*V1.y + C0.z*V2.y + C0.w*V3.y                   \
           + C1.x*V4.y + C1.y*V5.y + C1.z*V6.y + C1.w*V7.y;                  \
    acc.z += C0.x*V0.z + C0.y*V1.z + C0.z*V2.z + C0.w*V3.z                   \
           + C1.x*V4.z + C1.y*V5.z + C1.z*V6.z + C1.w*V7.z;                  \
    acc.w += C0.x*V0.w + C0.y*V1.w + C0.z*V2.w + C0.w*V3.w                   \
           + C1.x*V4.w + C1.y*V5.w + C1.z*V6.w + C1.w*V7.w;

__global__ __launch_bounds__(256) void k_gatherF(
    const int* __restrict__ ptr, const int* __restrict__ hist,
    const int* __restrict__ meta, const float* __restrict__ basis,
    const float* __restrict__ att, const float* __restrict__ root,
    const float* __restrict__ bias, float* __restrict__ agg)
{
    __shared__ float att_s[N_REL * N_BASES];
    int tid = threadIdx.x;
    for (int i = tid; i < N_REL * N_BASES; i += 256) att_s[i] = att[i];
    __syncthreads();

    int wid  = (int)((blockIdx.x * 256 + tid) >> 6);
    int lane = tid & 63;
    if (wid >= N_ENTITY) return;

    int half = lane >> 5;
    int l32  = lane & 31;
    int p   = ptr[wid];
    int cnt = hist[wid];
    const size_t bstride = (size_t)N_ENTITY * DIM;

    float4 acc = {0.f, 0.f, 0.f, 0.f};
    int j = 0;
    for (; j < cnt; j += 2) {
        int m0 = meta[p + j];
        bool has1 = (j + 1 < cnt);
        int m1 = has1 ? meta[p + j + 1] : m0;
        int m = half ? m1 : m0;
        float sc = (half && !has1) ? 0.0f : 1.0f;
        const float* bA = basis + (size_t)(m >> 6) * DIM + l32 * 4;
        float4 a0 = *(const float4*)(bA + 0 * bstride);
        float4 a1 = *(const float4*)(bA + 1 * bstride);
        float4 a2 = *(const float4*)(bA + 2 * bstride);
        float4 a3 = *(const float4*)(bA + 3 * bstride);
        float4 a4 = *(const float4*)(bA + 4 * bstride);
        float4 a5 = *(const float4*)(bA + 5 * bstride);
        float4 a6 = *(const float4*)(bA + 6 * bstride);
        float4 a7 = *(const float4*)(bA + 7 * bstride);
        float4 c0 = *(const float4*)(att_s + (m & 63) * N_BASES);
        float4 c1 = *(const float4*)(att_s + (m & 63) * N_BASES + 4);
        c0.x *= sc; c0.y *= sc; c0.z *= sc; c0.w *= sc;
        c1.x *= sc; c1.y *= sc; c1.z *= sc; c1.w *= sc;
        ACC8(c0, c1, a0, a1, a2, a3, a4, a5, a6, a7)
    }

    acc.x += __shfl_xor(acc.x, 32, 64);
    acc.y += __shfl_xor(acc.y, 32, 64);
    acc.z += __shfl_xor(acc.z, 32, 64);
    acc.w += __shfl_xor(acc.w, 32, 64);

    if (half == 0) {
        float inv = 1.0f / fmaxf((float)cnt, 1.0f);
        int o = wid * DIM + l32 * 4;
        float4 r  = *(const float4*)(root + o);
        float4 bb = *(const float4*)(bias + l32 * 4);
        float4 outv;
        outv.x = acc.x * inv + r.x + bb.x;
        outv.y = acc.y * inv + r.y + bb.y;
        outv.z = acc.z * inv + r.z + bb.z;
        outv.w = acc.w * inv + r.w + bb.w;
        *(float4*)(agg + o) = outv;
    }
}

// ===========================================================================
extern "C" void kernel_launch(void* const* d_in, const int* in_sizes, int n_in,
                              void* d_out, int out_size, void* d_ws, size_t ws_size,
                              hipStream_t stream)
{
    const int*   seed_ids  = (const int*)d_in[0];
    const int*   esrc      = (const int*)d_in[1];
    const int*   edst      = (const int*)d_in[2];
    const int*   etype     = (const int*)d_in[3];
    const float* basis     = (const float*)d_in[4];
    const float* att       = (const float*)d_in[5];
    const float* root      = (const float*)d_in[6];
    const float* rgcn_bias = (const float*)d_in[7];
    const float* attn_a    = (const float*)d_in[8];
    const float* attn_b    = (const float*)d_in[9];
    const float* out_bias  = (const float*)d_in[10];
    float* out = (float*)d_out;

    const size_t AGG_F  = (size_t)N_ENTITY * DIM;        // 8,239,104 words
    const size_t B16_W  = (size_t)N_ENTITY * 512;        // fp16 basis16 in words
    const size_t SLOT_W = (size_t)NPAD * CAP;            // 4,128,768

    const size_t main_words = AGG_F + B16_W + NPAD + 16 + 2 * OVF_CAP
                            + SLOT_W + 2 * BATCH * DIM + 64;
    bool big = ws_size >= main_words * 4;

    if (big) {
        float*  agg     = (float*)d_ws;
        __half* basis16 = (__half*)(agg + AGG_F);
        int*    cnt     = (int*)(agg + AGG_F + B16_W);
        int*    novf    = cnt + NPAD;
        int*    ovf     = novf + 16;
        int*    slots   = ovf + 2 * OVF_CAP;
        float*  uT      = (float*)(slots + SLOT_W);

        hipMemsetAsync(cnt, 0, (NPAD + 16) * sizeof(int), stream);
        k_prep<<<SCAT_BLOCKS + CVT_BLOCKS, 256, 0, stream>>>(
            esrc, edst, etype, basis, basis16, cnt, novf, ovf, slots);
        k_gather16<<<(N_ENTITY * 64 + 255) / 256, 256, 0, stream>>>(
            cnt, novf, ovf, slots, basis16, att, root, rgcn_bias, agg);
        k_attn<<<BATCH, 256, 0, stream>>>(seed_ids, agg, attn_a, attn_b, uT);
        k_scores<<<(N_ENTITY + 63) / 64, 256, 0, stream>>>(agg, uT, out_bias, out);
    } else {
        // fallback: dst counting-sort + fp32 gather
        float* agg   = (float*)d_ws;
        int*   hist  = (int*)(agg + AGG_F);     // NPAD
        int*   ptr   = hist + NPAD;
        int*   work  = ptr + NPAD;
        int*   part  = work + NPAD;             // 256
        int*   meta  = part + 256;              // N_EDGES
        float* uT    = (float*)(meta + N_EDGES);

        hipMemsetAsync(hist, 0, NPAD * sizeof(int), stream);
        k_histF<<<(N_EDGES + 255) / 256, 256, 0, stream>>>(edst, hist);
        k_scan1F<<<SCAN_NB, 256, 0, stream>>>(hist, ptr, part);
        k_scan23F<<<SCAN_NB, 256, 0, stream>>>(ptr, part, work);
        k_scatterF<<<(N_EDGES + 255) / 256, 256, 0, stream>>>(
            esrc, edst, etype, work, meta);
        k_gatherF<<<(N_ENTITY * 64 + 255) / 256, 256, 0, stream>>>(
            ptr, hist, meta, basis, att, root, rgcn_bias, agg);
        k_attn<<<BATCH, 256, 0, stream>>>(seed_ids, agg, attn_a, attn_b, uT);
        k_scores<<<(N_ENTITY + 63) / 64, 256, 0, stream>>>(agg, uT, out_bias, out);
    }
}